// Round 2
// 1277.068 us; speedup vs baseline: 1.6560x; 1.6560x over previous
//
#include <hip/hip_runtime.h>

#define V_N    20000
#define NNZ_N  640000
#define B_N    16
#define CIN_N  128
#define COUT_N 128
#define F_N    2048   // B*CIN = features per vertex

typedef unsigned int u32;
typedef unsigned short u16;
typedef __attribute__((ext_vector_type(8))) short short8;
typedef __attribute__((ext_vector_type(4))) float floatx4;

// bf16 helpers: storage is raw u16/u32 words; math is fp32.
__device__ __forceinline__ float bf_lo(u32 w) { return __uint_as_float(w << 16); }
__device__ __forceinline__ float bf_hi(u32 w) { return __uint_as_float(w & 0xffff0000u); }
__device__ __forceinline__ u16 f2bf(float f) {   // round-to-nearest-even
    u32 u = __float_as_uint(f);
    u += 0x7fffu + ((u >> 16) & 1u);
    return (u16)(u >> 16);
}
__device__ __forceinline__ u32 pack2(float a, float b) {
    return (u32)f2bf(a) | ((u32)f2bf(b) << 16);
}

// async global->LDS, 16B per lane; LDS dest = wave-uniform base + lane*16
__device__ __forceinline__ void gload_lds16(const void* g, void* l)
{
    __builtin_amdgcn_global_load_lds(
        (const __attribute__((address_space(1))) u32*)g,
        (__attribute__((address_space(3))) u32*)l, 16, 0, 0);
}

// ---------------------------------------------------------------------------
// Transpose fp32 (R x C) -> bf16 (C x R)
// ---------------------------------------------------------------------------
__global__ __launch_bounds__(256) void k_transpose_f2h(const float* __restrict__ in,
                                                       u16* __restrict__ out,
                                                       int R, int C)
{
    __shared__ float tile[32][33];
    int cb = blockIdx.x * 32;
    int rb = blockIdx.y * 32;
    int tx = threadIdx.x, ty = threadIdx.y;
#pragma unroll
    for (int j = 0; j < 4; ++j) {
        int r = rb + ty + j * 8, c = cb + tx;
        if (r < R && c < C) tile[ty + j * 8][tx] = in[(size_t)r * C + c];
    }
    __syncthreads();
#pragma unroll
    for (int j = 0; j < 4; ++j) {
        int c = cb + ty + j * 8, r = rb + tx;
        if (r < R && c < C) out[(size_t)c * R + r] = f2bf(tile[tx][ty + j * 8]);
    }
}

// ---------------------------------------------------------------------------
// CSR build: histogram -> scan -> scatter (counts doubles as cursor)
// ---------------------------------------------------------------------------
__global__ __launch_bounds__(256) void k_hist(const int* __restrict__ rows,
                                              int* __restrict__ counts)
{
    int i = blockIdx.x * 256 + threadIdx.x;
    if (i < NNZ_N) atomicAdd(&counts[rows[i]], 1);
}

__global__ __launch_bounds__(1024) void k_scan(int* __restrict__ counts,
                                               int* __restrict__ row_ptr)
{
    const int C = 20;
    __shared__ int sd[1024];
    int t = threadIdx.x;
    int beg = t * C;
    int end = beg + C; if (end > V_N) end = V_N;
    if (beg > V_N) beg = V_N;
    int s = 0;
    for (int i = beg; i < end; ++i) s += counts[i];
    sd[t] = s;
    __syncthreads();
    for (int off = 1; off < 1024; off <<= 1) {
        int add = (t >= off) ? sd[t - off] : 0;
        __syncthreads();
        sd[t] += add;
        __syncthreads();
    }
    int run = sd[t] - s;
    for (int i = beg; i < end; ++i) {
        int cnt = counts[i];
        row_ptr[i] = run;
        counts[i]  = run;     // becomes scatter cursor
        run += cnt;
    }
    if (t == 0) row_ptr[V_N] = NNZ_N;
}

__global__ __launch_bounds__(256) void k_scatter(const int* __restrict__ rows,
                                                 const int* __restrict__ cols_in,
                                                 const float* __restrict__ vals_in,
                                                 int* __restrict__ cursor,
                                                 int* __restrict__ csr_col,
                                                 float* __restrict__ csr_val)
{
    int i = blockIdx.x * 256 + threadIdx.x;
    if (i < NNZ_N) {
        int r = rows[i];
        int p = atomicAdd(&cursor[r], 1);
        csr_col[p] = cols_in[i];
        csr_val[p] = vals_in[i];
    }
}

// ---------------------------------------------------------------------------
// Feature-sliced SpMM over bf16 planes, fp32 accumulate.
//   slice = 64 features (128 B/row) -> slice plane 2.56 MB, fits one XCD L2.
//   XCD partition: blockIdx%8 -> XCD (heuristic); each XCD owns 4 slices.
//   8 threads per vertex row; col/val broadcast via shfl within the 8-group.
//   cheb=0: dst = L*src ;  cheb=1: dst = 2*L*src - old
// ---------------------------------------------------------------------------
__device__ __forceinline__ void acc8(float* acc, float s, uint4 q)
{
    acc[0] += s * bf_lo(q.x); acc[1] += s * bf_hi(q.x);
    acc[2] += s * bf_lo(q.y); acc[3] += s * bf_hi(q.y);
    acc[4] += s * bf_lo(q.z); acc[5] += s * bf_hi(q.z);
    acc[6] += s * bf_lo(q.w); acc[7] += s * bf_hi(q.w);
}

__global__ __launch_bounds__(256) void k_spmm_s(const u16* __restrict__ src,
                                                u16* __restrict__ dst,
                                                const u16* __restrict__ oldp,
                                                const int* __restrict__ row_ptr,
                                                const int* __restrict__ csr_col,
                                                const float* __restrict__ csr_val,
                                                int cheb)
{
    int n = blockIdx.x;               // 0..19999
    int m = n >> 3;                   // 0..2499 within XCD
    int slice = (n & 7) * 4 + m / 625;  // XCD owns 4 consecutive slices
    int chunk = m % 625;              // 32-vertex chunk
    int tid = threadIdx.x;
    int sub = tid & 7;                // feature sub-chunk within slice
    int v   = chunk * 32 + (tid >> 3);
    size_t fo = (size_t)slice * 64 + sub * 8;

    int jb = row_ptr[v], je = row_ptr[v + 1];
    float acc[8] = {0.f, 0.f, 0.f, 0.f, 0.f, 0.f, 0.f, 0.f};
    const u16* sp = src + fo;

    for (int j0 = jb; j0 < je; j0 += 8) {
        int idx = j0 + sub;
        int cc = 0; float vv = 0.f;
        if (idx < je) { cc = csr_col[idx]; vv = csr_val[idx]; }
        int nrem = je - j0;
        if (nrem >= 8) {
#pragma unroll
            for (int t = 0; t < 8; ++t) {
                int   col = __shfl(cc, t, 8);
                float s   = __shfl(vv, t, 8);
                uint4 q = *reinterpret_cast<const uint4*>(sp + (size_t)col * F_N);
                acc8(acc, s, q);
            }
        } else {
            for (int t = 0; t < nrem; ++t) {
                int   col = __shfl(cc, t, 8);
                float s   = __shfl(vv, t, 8);
                uint4 q = *reinterpret_cast<const uint4*>(sp + (size_t)col * F_N);
                acc8(acc, s, q);
            }
        }
    }

    u16* dp = dst + (size_t)v * F_N + fo;
    if (cheb) {
        uint4 oq = *reinterpret_cast<const uint4*>(oldp + (size_t)v * F_N + fo);
        float od[8];
        od[0] = bf_lo(oq.x); od[1] = bf_hi(oq.x);
        od[2] = bf_lo(oq.y); od[3] = bf_hi(oq.y);
        od[4] = bf_lo(oq.z); od[5] = bf_hi(oq.z);
        od[6] = bf_lo(oq.w); od[7] = bf_hi(oq.w);
#pragma unroll
        for (int t = 0; t < 8; ++t) acc[t] = 2.f * acc[t] - od[t];
    }
    uint4 o;
    o.x = pack2(acc[0], acc[1]);
    o.y = pack2(acc[2], acc[3]);
    o.z = pack2(acc[4], acc[5]);
    o.w = pack2(acc[6], acc[7]);
    *reinterpret_cast<uint4*>(dp) = o;
}

// ---------------------------------------------------------------------------
// W prep: weight fp32 (R,CIN,COUT) -> Wt bf16 [o=128][k=R*CIN=512]  (B^T layout)
// ---------------------------------------------------------------------------
__global__ __launch_bounds__(256) void k_wprep(const float* __restrict__ w,
                                               u16* __restrict__ wt)
{
    int i = blockIdx.x * 256 + threadIdx.x;   // 0..65535
    int o = i >> 9, k = i & 511;
    wt[i] = f2bf(w[(size_t)k * COUT_N + o]);
}

// ---------------------------------------------------------------------------
// Fused MFMA GEMM: out[b,o,v] = bias[o] + sum_{k=0..511} h_{k/128}[v, b*128+k%128] * W[k,o]
// Tile 128v x 128o, BK=64, 4 waves (2x2, 64x64 each), 16x16x32 bf16 MFMA.
// LDS XOR-swizzle (chunk ^= row&7) applied on BOTH the pre-swizzled global
// source for global_load_lds (linear dest) and the ds_read_b128 address.
// Output stored directly in (B, Cout, V) layout (D rows = v, lane-consecutive).
// ---------------------------------------------------------------------------
__global__ __launch_bounds__(256) void k_gemm_fused(const u16* __restrict__ h0,
                                                    const u16* __restrict__ h1,
                                                    const u16* __restrict__ h2,
                                                    const u16* __restrict__ h3,
                                                    const u16* __restrict__ wt,
                                                    const float* __restrict__ bias,
                                                    float* __restrict__ out)
{
    __shared__ __align__(16) u16 At[128 * 64];   // 16 KB, swizzled rows of 128 B
    __shared__ __align__(16) u16 Wl[128 * 64];   // 16 KB

    const u16* const planes[4] = {h0, h1, h2, h3};

    const int tid  = threadIdx.x;
    const int v0   = blockIdx.x * 128;
    const int b    = blockIdx.y;
    const int wave = tid >> 6;
    const int wm   = wave >> 1;        // 0..1 : v-half
    const int wn   = wave & 1;         // 0..1 : o-half
    const int l15  = tid & 15;
    const int l4   = (tid & 63) >> 4;  // 0..3

    const int srow = tid >> 3;         // staging row within 32-row group
    const int sch  = tid & 7;          // staging 16B chunk slot

    floatx4 c[4][4];
#pragma unroll
    for (int fn = 0; fn < 4; ++fn) {
        float bo = bias[wn * 64 + fn * 16 + l15];
#pragma unroll
        for (int fm = 0; fm < 4; ++fm) c[fm][fn] = (floatx4){bo, bo, bo, bo};
    }

#pragma unroll
    for (int kt = 0; kt < 8; ++kt) {
        const u16* plane = planes[kt >> 1];
        const int  i0    = (kt & 1) * 64;
        const int  k0    = kt * 64;
        __syncthreads();
#pragma unroll
        for (int it = 0; it < 4; ++it) {
            int row = it * 32 + srow;                 // v-local 0..127
            int cch = sch ^ (row & 7);                // pre-swizzled source chunk
            const u16* g = plane + (size_t)(v0 + row) * F_N + b * 128 + i0 + cch * 8;
            char* l = (char*)At + it * 4096 + (tid >> 6) * 1024;
            if (v0 + row < V_N) gload_lds16(g, l);
        }
#pragma unroll
        for (int it = 0; it < 4; ++it) {
            int row = it * 32 + srow;                 // o 0..127
            int cch = sch ^ (row & 7);
            const u16* g = wt + (size_t)row * 512 + k0 + cch * 8;
            char* l = (char*)Wl + it * 4096 + (tid >> 6) * 1024;
            gload_lds16(g, l);
        }
        __syncthreads();
#pragma unroll
        for (int k32 = 0; k32 < 2; ++k32) {
            short8 af[4], bf[4];
#pragma unroll
            for (int fm = 0; fm < 4; ++fm) {
                int row = wm * 64 + fm * 16 + l15;
                int ch  = k32 * 4 + l4;
                af[fm] = *reinterpret_cast<const short8*>(
                    (const char*)At + row * 128 + ((ch ^ (row & 7)) * 16));
            }
#pragma unroll
            for (int fn = 0; fn < 4; ++fn) {
                int row = wn * 64 + fn * 16 + l15;
                int ch  = k32 * 4 + l4;
                bf[fn] = *reinterpret_cast<const short8*>(
                    (const char*)Wl + row * 128 + ((ch ^ (row & 7)) * 16));
            }
#pragma unroll
            for (int fm = 0; fm < 4; ++fm)
#pragma unroll
                for (int fn = 0; fn < 4; ++fn)
                    c[fm][fn] = __builtin_amdgcn_mfma_f32_16x16x32_bf16(
                        af[fm], bf[fn], c[fm][fn], 0, 0, 0);
        }
    }

    // D layout: col = lane&15 = o, row = (lane>>4)*4 + reg = v  ->  float4 along v
#pragma unroll
    for (int fm = 0; fm < 4; ++fm) {
        int v = v0 + wm * 64 + fm * 16 + l4 * 4;
        if (v < V_N) {
#pragma unroll
            for (int fn = 0; fn < 4; ++fn) {
                int o = wn * 64 + fn * 16 + l15;
                *reinterpret_cast<floatx4*>(out + (size_t)(b * 128 + o) * V_N + v) = c[fm][fn];
            }
        }
    }
}

// ---------------------------------------------------------------------------
extern "C" void kernel_launch(void* const* d_in, const int* in_sizes, int n_in,
                              void* d_out, int out_size, void* d_ws, size_t ws_size,
                              hipStream_t stream)
{
    const float* x        = (const float*)d_in[0];
    const float* weight   = (const float*)d_in[1];
    const float* bias     = (const float*)d_in[2];
    const float* lap_vals = (const float*)d_in[3];
    const int*   lap_rows = (const int*)d_in[4];
    const int*   lap_cols = (const int*)d_in[5];
    float* out = (float*)d_out;

    // workspace: 4 bf16 planes (x0..x3) + CSR scratch (~333 MB total)
    size_t plane = (size_t)V_N * F_N;
    u16* h0 = (u16*)d_ws;
    u16* h1 = h0 + plane;
    u16* h2 = h1 + plane;
    u16* h3 = h2 + plane;
    int*   counts  = (int*)(h3 + plane);
    int*   row_ptr = counts + V_N;
    int*   csr_col = row_ptr + V_N + 16;        // +16 keeps csr_col 16B-aligned
    float* csr_val = (float*)(csr_col + NNZ_N);
    u16*   wt      = (u16*)csr_col;             // aliased: used only after SpMMs

    // --- CSR build ---
    (void)hipMemsetAsync(counts, 0, V_N * sizeof(int), stream);
    k_hist<<<(NNZ_N + 255) / 256, 256, 0, stream>>>(lap_rows, counts);
    k_scan<<<1, 1024, 0, stream>>>(counts, row_ptr);
    k_scatter<<<(NNZ_N + 255) / 256, 256, 0, stream>>>(lap_rows, lap_cols, lap_vals,
                                                       counts, csr_col, csr_val);

    // --- h0 = bf16(transpose(x)) : (2048, V) -> (V, 2048) ---
    k_transpose_f2h<<<dim3(V_N / 32, F_N / 32), dim3(32, 8), 0, stream>>>(x, h0, F_N, V_N);

    // --- Chebyshev planes (feature-sliced SpMM) ---
    k_spmm_s<<<V_N, 256, 0, stream>>>(h0, h1, (const u16*)0, row_ptr, csr_col, csr_val, 0);
    k_spmm_s<<<V_N, 256, 0, stream>>>(h1, h2, h0, row_ptr, csr_col, csr_val, 1);
    k_spmm_s<<<V_N, 256, 0, stream>>>(h2, h3, h1, row_ptr, csr_col, csr_val, 1);

    // --- W -> bf16 [o][k] (over dead CSR col space), then fused MFMA GEMM ---
    k_wprep<<<(512 * 128) / 256, 256, 0, stream>>>(weight, wt);
    k_gemm_fused<<<dim3((V_N + 127) / 128, B_N), 256, 0, stream>>>(
        h0, h1, h2, h3, wt, bias, out);
}